// Round 6
// baseline (488.943 us; speedup 1.0000x reference)
//
#include <hip/hip_runtime.h>

// Problem constants
#define N_NODES    117760
#define N_EDGES    3768320
#define IN_FEAT    115
#define HIDDEN     64
#define NPG        115
#define NUM_GRAPHS 1024
#define HC2        256
#define FDIM       (NPG*HIDDEN)   // 7360
#define NB         460            // buckets (N_NODES / 256 exactly)
#define RPB        8192           // edges per partition block (N_EDGES/RPB = 460)
#define SORT_CAP   9216           // per-bucket LDS capacity (mean 8192, sd ~90: +11 sigma)

// adj entry: .x = src | (dstlow<<17)  (src < 2^17, dstlow < 256), .y = bits(ew)

__device__ __forceinline__ float bf2f(unsigned short u) {
    return __uint_as_float(((unsigned)u) << 16);
}
__device__ __forceinline__ unsigned short f2bf(float f) {
    unsigned x = __float_as_uint(f);
    unsigned r = x + 0x7FFFu + ((x >> 16) & 1u);   // RNE
    return (unsigned short)(r >> 16);
}

// ---- pass 1: bucket histogram + weighted degree (global atomics) ----
__global__ __launch_bounds__(256) void k_histdeg(const int* __restrict__ ei,
                                                 const float* __restrict__ ew,
                                                 unsigned* __restrict__ ghist,
                                                 float* __restrict__ deg) {
    __shared__ unsigned lh[NB];
    for (int i = threadIdx.x; i < NB; i += 256) lh[i] = 0;
    __syncthreads();
    const int e0 = blockIdx.x * RPB;
    #pragma unroll 4
    for (int i = 0; i < RPB / 256; ++i) {
        const int e = e0 + i * 256 + threadIdx.x;
        const int dst = ei[N_EDGES + e];
        atomicAdd(&lh[dst >> 8], 1u);
        atomicAdd(&deg[dst], ew[e]);
    }
    __syncthreads();
    for (int i = threadIdx.x; i < NB; i += 256) atomicAdd(&ghist[i], lh[i]);
}

// ---------------- pass 2: exclusive scan -> base, cursor ----------------
__global__ __launch_bounds__(512) void k_scan(const unsigned* __restrict__ ghist,
                                              unsigned* __restrict__ base,
                                              unsigned* __restrict__ cursor) {
    __shared__ unsigned s[512];
    const int t = threadIdx.x;
    unsigned v = (t < NB) ? ghist[t] : 0u;
    s[t] = v; __syncthreads();
    for (int off = 1; off < 512; off <<= 1) {
        unsigned u = (t >= off) ? s[t - off] : 0u;
        __syncthreads();
        s[t] += u;
        __syncthreads();
    }
    if (t < NB) { unsigned ex = s[t] - v; base[t] = ex; cursor[t] = ex; }
    if (t == NB - 1) base[NB] = s[t];
}

// ---------------- pass 3: LDS-staged multisplit partition (by bucket) ----
__global__ __launch_bounds__(512) void k_part(const int* __restrict__ ei,
                                              const float* __restrict__ ew,
                                              unsigned* __restrict__ cursor,
                                              uint2* __restrict__ adj) {
    __shared__ uint2         sbuf[RPB];        // 64 KB
    __shared__ unsigned char sbkt[RPB];        // 8 KB
    __shared__ unsigned      lb[NB + 1], lc[NB], gp[NB];
    __shared__ unsigned      sc[512];
    const int t = threadIdx.x;
    sc[t] = 0;
    for (int i = t; i < NB; i += 512) lc[i] = 0;
    __syncthreads();
    const int e0 = blockIdx.x * RPB;
    #pragma unroll 4
    for (int i = 0; i < RPB / 512; ++i) {
        int dst = ei[N_EDGES + e0 + i * 512 + t];
        atomicAdd(&sc[dst >> 8], 1u);
    }
    __syncthreads();
    const unsigned v = sc[t];
    __syncthreads();
    for (int off = 1; off < 512; off <<= 1) {
        unsigned u = (t >= off) ? sc[t - off] : 0u;
        __syncthreads();
        sc[t] += u;
        __syncthreads();
    }
    if (t < NB) lb[t] = sc[t] - v;
    if (t == NB - 1) lb[NB] = sc[t];
    if (t < NB) gp[t] = atomicAdd(&cursor[t], v);
    __syncthreads();
    #pragma unroll 2
    for (int i = 0; i < RPB / 512; ++i) {
        int e   = e0 + i * 512 + t;
        int src = ei[e];
        int dst = ei[N_EDGES + e];
        float w = ew[e];
        int b = dst >> 8;
        unsigned pos = lb[b] + atomicAdd(&lc[b], 1u);
        sbuf[pos] = make_uint2((unsigned)src | ((unsigned)(dst & 255) << 17),
                               __float_as_uint(w));
        sbkt[pos] = (unsigned char)b;
    }
    __syncthreads();
    for (int k = t; k < RPB; k += 512) {
        int b = (int)sbkt[k];
        if ((unsigned)k >= lb[b + 1]) b += 256;   // low-8 disambiguation
        adj[gp[b] + ((unsigned)k - lb[b])] = sbuf[k];
    }
}

// ------- h2 = (x @ W1) * rsqrt(deg+1)  (fp32 compute, bf16 store) -------
__global__ __launch_bounds__(256) void k_h(const float* __restrict__ x,
                                           const float* __restrict__ W1,
                                           const float* __restrict__ deg,
                                           unsigned short* __restrict__ hb2) {
    __shared__ float w1s[IN_FEAT * HIDDEN];
    __shared__ float xs[64 * IN_FEAT];
    for (int i = threadIdx.x; i < IN_FEAT * HIDDEN; i += 256) w1s[i] = W1[i];
    const int tr = threadIdx.x >> 4;
    const int tc = threadIdx.x & 15;
    for (int t = blockIdx.x; t < N_NODES / 64; t += gridDim.x) {
        const int row0 = t * 64;
        __syncthreads();
        for (int i = threadIdx.x; i < 64 * IN_FEAT; i += 256)
            xs[i] = x[row0 * IN_FEAT + i];
        __syncthreads();
        float acc[4][4] = {};
        for (int k = 0; k < IN_FEAT; ++k) {
            const float4 wv = *(const float4*)&w1s[k * HIDDEN + tc * 4];
            #pragma unroll
            for (int i = 0; i < 4; ++i) {
                const float xv = xs[(tr * 4 + i) * IN_FEAT + k];
                acc[i][0] += xv * wv.x;
                acc[i][1] += xv * wv.y;
                acc[i][2] += xv * wv.z;
                acc[i][3] += xv * wv.w;
            }
        }
        #pragma unroll
        for (int i = 0; i < 4; ++i) {
            const int row = row0 + tr * 4 + i;
            const float dn = rsqrtf(deg[row] + 1.0f);
            ushort4 v;
            v.x = f2bf(acc[i][0] * dn); v.y = f2bf(acc[i][1] * dn);
            v.z = f2bf(acc[i][2] * dn); v.w = f2bf(acc[i][3] * dn);
            *(ushort4*)&hb2[(size_t)row * HIDDEN + tc * 4] = v;
        }
    }
}

// ---------------- W23 = W2 @ W3 ; c0 = b2.W3 + b3 ----------------
__global__ __launch_bounds__(256) void k_w23(const float* __restrict__ W2,
                                             const float* __restrict__ W3,
                                             const float* __restrict__ b2,
                                             const float* __restrict__ b3,
                                             float* __restrict__ W23,
                                             float* __restrict__ c0) {
    const int wid  = blockIdx.x * 4 + (threadIdx.x >> 6);
    const int lane = threadIdx.x & 63;
    if (wid < FDIM) {
        float acc = 0.f;
        #pragma unroll
        for (int c = lane; c < HC2; c += 64) acc += W2[wid * HC2 + c] * W3[c];
        #pragma unroll
        for (int off = 32; off; off >>= 1) acc += __shfl_down(acc, off);
        if (lane == 0) W23[wid] = acc;
    } else if (wid == FDIM) {
        float acc = 0.f;
        #pragma unroll
        for (int c = lane; c < HC2; c += 64) acc += b2[c] * W3[c];
        #pragma unroll
        for (int off = 32; off; off >>= 1) acc += __shfl_down(acc, off);
        if (lane == 0) c0[0] = acc + b3[0];
    }
}

// ---------------- out[g] = c0 ----------------
__global__ __launch_bounds__(256) void k_initout(const float* __restrict__ c0,
                                                 float* __restrict__ out) {
    int g = blockIdx.x * 256 + threadIdx.x;
    if (g < NUM_GRAPHS) out[g] = c0[0];
}

// quarter-wave quad step: lane's record (uint2) -> 8B row slice, 4 FMAs
__device__ __forceinline__ void quad(const uint2 r,
                                     const unsigned short* __restrict__ hb2,
                                     int fq, float4& acc) {
    const unsigned row = r.x & 0x1FFFF;
    const float w = __uint_as_float(r.y);
    const ushort4 hv = *(const ushort4*)(hb2 + (size_t)row * HIDDEN + fq * 4);
    acc.x += w * bf2f(hv.x); acc.y += w * bf2f(hv.y);
    acc.z += w * bf2f(hv.z); acc.w += w * bf2f(hv.w);
}

// per-node epilogue: cross-group reduce, self-loop, relu+b1, dot W23, out atomic
__device__ __forceinline__ void epi(float4 acc, int n, int fq, int lane,
                                    const float* __restrict__ deg,
                                    const unsigned short* __restrict__ hb2,
                                    float4 b1q, const float* __restrict__ W23,
                                    float* __restrict__ out) {
    acc.x += __shfl_xor(acc.x, 16); acc.y += __shfl_xor(acc.y, 16);
    acc.z += __shfl_xor(acc.z, 16); acc.w += __shfl_xor(acc.w, 16);
    acc.x += __shfl_xor(acc.x, 32); acc.y += __shfl_xor(acc.y, 32);
    acc.z += __shfl_xor(acc.z, 32); acc.w += __shfl_xor(acc.w, 32);
    const float dn = rsqrtf(deg[n] + 1.0f);
    const ushort4 hs = *(const ushort4*)(hb2 + (size_t)n * HIDDEN + fq * 4);
    float4 v;
    v.x = fmaxf((acc.x + bf2f(hs.x)) * dn + b1q.x, 0.f);
    v.y = fmaxf((acc.y + bf2f(hs.y)) * dn + b1q.y, 0.f);
    v.z = fmaxf((acc.z + bf2f(hs.z)) * dn + b1q.z, 0.f);
    v.w = fmaxf((acc.w + bf2f(hs.w)) * dn + b1q.w, 0.f);
    const int g = n / NPG, r = n - g * NPG;
    const float4 wv = *(const float4*)(W23 + r * HIDDEN + fq * 4);
    float p = v.x * wv.x + v.y * wv.y + v.z * wv.z + v.w * wv.w;
    p += __shfl_xor(p, 1); p += __shfl_xor(p, 2);
    p += __shfl_xor(p, 4); p += __shfl_xor(p, 8);
    if (lane == 0) atomicAdd(&out[g], p);
}

// ---- pass 4 (fused): per-bucket LDS sort -> gather from LDS records ----
__global__ __launch_bounds__(512) void k_sortgather(
        const uint2* __restrict__ adj, const unsigned* __restrict__ base,
        const float* __restrict__ deg, const unsigned short* __restrict__ hb2,
        const float* __restrict__ b1, const float* __restrict__ W23,
        float* __restrict__ out) {
    __shared__ uint2    sbuf[SORT_CAP + 4];   // 73,760 B
    __shared__ unsigned lh[256], lb[257], lcc[256];
    __shared__ unsigned sc[512];
    const int t = threadIdx.x, b = blockIdx.x;
    const unsigned s0 = base[b], s1 = base[b + 1];
    const int bsz = (int)(s1 - s0);
    if (t < 256) { lh[t] = 0; lcc[t] = 0; }
    __syncthreads();
    // hist over dstlow
    for (unsigned k = s0 + t; k < s1; k += 512)
        atomicAdd(&lh[adj[k].x >> 17], 1u);
    __syncthreads();
    // exclusive scan -> local per-node offsets
    unsigned v = (t < 256) ? lh[t] : 0u;
    sc[t] = v; __syncthreads();
    for (int off = 1; off < 256; off <<= 1) {
        unsigned u = (t >= off && t < 256) ? sc[t - off] : 0u;
        __syncthreads();
        if (t < 256) sc[t] += u;
        __syncthreads();
    }
    if (t < 256) lb[t] = sc[t] - v;
    if (t == 255) lb[256] = sc[255];
    __syncthreads();
    const bool sorted = (bsz <= SORT_CAP);
    if (sorted) {
        for (unsigned k = s0 + t; k < s1; k += 512) {
            uint2 e = adj[k];
            unsigned dl = e.x >> 17;
            sbuf[lb[dl] + atomicAdd(&lcc[dl], 1u)] = e;
        }
    }
    __syncthreads();

    const int wave = t >> 6, lane = t & 63;
    const int grp = lane >> 4, fq = lane & 15;
    const float4 b1q = *(const float4*)(b1 + fq * 4);
    const int nbase = b * 256;

    if (sorted) {
        // 8 waves x 16 node-pairs; 2 streams/wave, 4 edges per load
        for (int p2 = 0; p2 < 16; ++p2) {
            const int na = wave * 32 + p2 * 2;
            unsigned ka = __builtin_amdgcn_readfirstlane(lb[na]);
            const unsigned ea = __builtin_amdgcn_readfirstlane(lb[na + 1]);
            unsigned kb = ea;
            const unsigned eb = __builtin_amdgcn_readfirstlane(lb[na + 2]);
            float4 accA = {0.f, 0.f, 0.f, 0.f}, accB = {0.f, 0.f, 0.f, 0.f};
            const int qa = (int)(ea - ka) >> 2, qb = (int)(eb - kb) >> 2;
            const int qmin = qa < qb ? qa : qb;
            for (int q = 0; q < qmin; ++q) {
                uint2 rA = sbuf[ka + grp];
                uint2 rB = sbuf[kb + grp];
                quad(rA, hb2, fq, accA);
                quad(rB, hb2, fq, accB);
                ka += 4; kb += 4;
            }
            for (int q = qmin; q < qa; ++q) {
                uint2 r = sbuf[ka + grp]; quad(r, hb2, fq, accA); ka += 4;
            }
            for (int q = qmin; q < qb; ++q) {
                uint2 r = sbuf[kb + grp]; quad(r, hb2, fq, accB); kb += 4;
            }
            const int remA = (int)(ea - ka);
            if (remA) {
                uint2 r = sbuf[ka + grp];
                if (grp >= remA) { r.x = 0u; r.y = 0u; }
                quad(r, hb2, fq, accA);
            }
            const int remB = (int)(eb - kb);
            if (remB) {
                uint2 r = sbuf[kb + grp];
                if (grp >= remB) { r.x = 0u; r.y = 0u; }
                quad(r, hb2, fq, accB);
            }
            epi(accA, nbase + na, fq, lane, deg, hb2, b1q, W23, out);
            epi(accB, nbase + na + 1, fq, lane, deg, hb2, b1q, W23, out);
        }
    } else {
        // fallback (statistically never): filter-scan whole bucket per node
        for (int dl = wave * 32; dl < wave * 32 + 32; ++dl) {
            float4 acc = {0.f, 0.f, 0.f, 0.f};
            for (unsigned k = s0; k < s1; k += 4) {
                const unsigned idx = k + grp;
                uint2 e = make_uint2(0u, 0u);
                if (idx < s1) e = adj[idx];
                const bool ok = (idx < s1) && ((int)(e.x >> 17) == dl);
                uint2 r;
                r.x = ok ? e.x : 0u;
                r.y = ok ? e.y : 0u;
                quad(r, hb2, fq, acc);
            }
            epi(acc, nbase + dl, fq, lane, deg, hb2, b1q, W23, out);
        }
    }
}

extern "C" void kernel_launch(void* const* d_in, const int* in_sizes, int n_in,
                              void* d_out, int out_size, void* d_ws, size_t ws_size,
                              hipStream_t stream) {
    const float* x  = (const float*)d_in[0];
    const int*   ei = (const int*)  d_in[1];
    const float* ew = (const float*)d_in[2];
    const float* W1 = (const float*)d_in[4];
    const float* b1 = (const float*)d_in[5];
    const float* W2 = (const float*)d_in[6];
    const float* b2 = (const float*)d_in[7];
    const float* W3 = (const float*)d_in[8];
    const float* b3 = (const float*)d_in[9];
    float* out = (float*)d_out;

    char* ws = (char*)d_ws;
    unsigned short* hb2  = (unsigned short*)(ws);              // 15,073,280
    uint2*          adj  = (uint2*)   (ws + 15073280);         // 30,146,560
    float*          deg  = (float*)   (ws + 45219840);         // 471,040
    unsigned*       ghist= (unsigned*)(ws + 45690880);         // 1,840
    unsigned*       base = (unsigned*)(ws + 45692720);         // 1,844
    unsigned*       cur  = (unsigned*)(ws + 45694564);         // 1,840
    float*          W23  = (float*)   (ws + 45696416);         // 29,440
    float*          c0   = (float*)   (ws + 45725856);         // 4

    // deg and ghist adjacent -> one memset clears both
    hipMemsetAsync(deg, 0, 471040 + 1840, stream);

    k_histdeg<<<NB, 256, 0, stream>>>(ei, ew, ghist, deg);
    k_scan   <<<1, 512, 0, stream>>>(ghist, base, cur);
    k_part   <<<NB, 512, 0, stream>>>(ei, ew, cur, adj);
    k_h      <<<512, 256, 0, stream>>>(x, W1, deg, hb2);
    k_w23    <<<(FDIM / 4) + 1, 256, 0, stream>>>(W2, W3, b2, b3, W23, c0);
    k_initout<<<4, 256, 0, stream>>>(c0, out);
    k_sortgather<<<NB, 512, 0, stream>>>(adj, base, deg, hb2, b1, W23, out);
}

// Round 7
// 442.054 us; speedup vs baseline: 1.1061x; 1.1061x over previous
//
#include <hip/hip_runtime.h>

// Problem constants
#define N_NODES    117760
#define N_EDGES    3768320
#define IN_FEAT    115
#define HIDDEN     64
#define NPG        115
#define NUM_GRAPHS 1024
#define HC2        256
#define FDIM       (NPG*HIDDEN)   // 7360
#define NB         460            // buckets (N_NODES / 256 exactly)
#define RPB        8192           // edges per partition block (N_EDGES/RPB = 460)
#define CAP        9216           // fixed bucket window (mean 8192, sd ~90: +11 sigma)

// adj/adj2 entry: .x = src | (dstlow<<17)  (src < 2^17, dstlow < 256), .y = bits(ew)

__device__ __forceinline__ float bf2f(unsigned short u) {
    return __uint_as_float(((unsigned)u) << 16);
}
__device__ __forceinline__ unsigned short f2bf(float f) {
    unsigned x = __float_as_uint(f);
    unsigned r = x + 0x7FFFu + ((x >> 16) & 1u);   // RNE
    return (unsigned short)(r >> 16);
}

// ---- init: bucket cursors to fixed windows ----
__global__ __launch_bounds__(256) void k_initcur(unsigned* __restrict__ cur) {
    int i = blockIdx.x * 256 + threadIdx.x;
    if (i < NB) cur[i] = (unsigned)i * CAP;
}

// ---- pass 1: LDS-staged multisplit partition into fixed bucket windows ----
__global__ __launch_bounds__(512) void k_part(const int* __restrict__ ei,
                                              const float* __restrict__ ew,
                                              unsigned* __restrict__ cur,
                                              uint2* __restrict__ adj) {
    __shared__ uint2         sbuf[RPB];        // 64 KB
    __shared__ unsigned char sbkt[RPB];        // 8 KB
    __shared__ unsigned      lb[NB + 1], lc[NB], gp[NB];
    __shared__ unsigned      sc[512];
    const int t = threadIdx.x;
    sc[t] = 0;
    for (int i = t; i < NB; i += 512) lc[i] = 0;
    __syncthreads();
    const int e0 = blockIdx.x * RPB;
    #pragma unroll 4
    for (int i = 0; i < RPB / 512; ++i) {
        int dst = ei[N_EDGES + e0 + i * 512 + t];
        atomicAdd(&sc[dst >> 8], 1u);
    }
    __syncthreads();
    const unsigned v = sc[t];
    __syncthreads();
    for (int off = 1; off < 512; off <<= 1) {
        unsigned u = (t >= off) ? sc[t - off] : 0u;
        __syncthreads();
        sc[t] += u;
        __syncthreads();
    }
    if (t < NB) lb[t] = sc[t] - v;
    if (t == NB - 1) lb[NB] = sc[t];
    if (t < NB) gp[t] = atomicAdd(&cur[t], v);
    __syncthreads();
    #pragma unroll 2
    for (int i = 0; i < RPB / 512; ++i) {
        int e   = e0 + i * 512 + t;
        int src = ei[e];
        int dst = ei[N_EDGES + e];
        float w = ew[e];
        int b = dst >> 8;
        unsigned pos = lb[b] + atomicAdd(&lc[b], 1u);
        sbuf[pos] = make_uint2((unsigned)src | ((unsigned)(dst & 255) << 17),
                               __float_as_uint(w));
        sbkt[pos] = (unsigned char)b;
    }
    __syncthreads();
    for (int k = t; k < RPB; k += 512) {
        int b = (int)sbkt[k];
        if ((unsigned)k >= lb[b + 1]) b += 256;   // low-8 disambiguation
        const unsigned gi = gp[b] + ((unsigned)k - lb[b]);
        if (gi < (unsigned)(b + 1) * CAP)         // capacity guard (never fires)
            adj[gi] = sbuf[k];
    }
}

// ---- pass 2: per-bucket LDS sort by dst -> adj2 + CSR (base2/ends) + deg ----
__global__ __launch_bounds__(512) void k_sort2(const uint2* __restrict__ adj,
                                               const unsigned* __restrict__ cur,
                                               uint2* __restrict__ adj2,
                                               unsigned* __restrict__ base2,
                                               unsigned* __restrict__ ends,
                                               float* __restrict__ deg) {
    __shared__ uint2    sbuf[CAP];        // 73,728 B
    __shared__ unsigned lh[256], lcc[256], lb[256];
    __shared__ float    sdeg[256];
    __shared__ unsigned sc[512];
    const int t = threadIdx.x, b = blockIdx.x;
    const unsigned s0 = (unsigned)b * CAP;
    unsigned size = cur[b] - s0;
    if (size > CAP) size = CAP;
    const unsigned s1 = s0 + size;
    if (t < 256) { lh[t] = 0; lcc[t] = 0; sdeg[t] = 0.f; }
    __syncthreads();
    for (unsigned k = s0 + t; k < s1; k += 512) {
        uint2 e = adj[k];
        unsigned dl = e.x >> 17;
        atomicAdd(&lh[dl], 1u);
        atomicAdd(&sdeg[dl], __uint_as_float(e.y));
    }
    __syncthreads();
    unsigned v = (t < 256) ? lh[t] : 0u;
    sc[t] = v; __syncthreads();
    for (int off = 1; off < 256; off <<= 1) {
        unsigned u = (t >= off && t < 256) ? sc[t - off] : 0u;
        __syncthreads();
        if (t < 256) sc[t] += u;
        __syncthreads();
    }
    if (t < 256) {
        lb[t] = sc[t] - v;
        base2[b * 256 + t] = s0 + sc[t] - v;
        ends [b * 256 + t] = s0 + sc[t];
        deg  [b * 256 + t] = sdeg[t];
    }
    __syncthreads();
    for (unsigned k = s0 + t; k < s1; k += 512) {
        uint2 e = adj[k];
        unsigned dl = e.x >> 17;
        sbuf[lb[dl] + atomicAdd(&lcc[dl], 1u)] = e;
    }
    __syncthreads();
    for (unsigned k = t; k < size; k += 512) adj2[s0 + k] = sbuf[k];
}

// ------- h2 = (x @ W1) * rsqrt(deg+1)  (fp32 compute, bf16 store) -------
__global__ __launch_bounds__(256) void k_h(const float* __restrict__ x,
                                           const float* __restrict__ W1,
                                           const float* __restrict__ deg,
                                           unsigned short* __restrict__ hb2) {
    __shared__ float w1s[IN_FEAT * HIDDEN];
    __shared__ float xs[64 * IN_FEAT];
    for (int i = threadIdx.x; i < IN_FEAT * HIDDEN; i += 256) w1s[i] = W1[i];
    const int tr = threadIdx.x >> 4;
    const int tc = threadIdx.x & 15;
    for (int t = blockIdx.x; t < N_NODES / 64; t += gridDim.x) {
        const int row0 = t * 64;
        __syncthreads();
        for (int i = threadIdx.x; i < 64 * IN_FEAT; i += 256)
            xs[i] = x[row0 * IN_FEAT + i];
        __syncthreads();
        float acc[4][4] = {};
        for (int k = 0; k < IN_FEAT; ++k) {
            const float4 wv = *(const float4*)&w1s[k * HIDDEN + tc * 4];
            #pragma unroll
            for (int i = 0; i < 4; ++i) {
                const float xv = xs[(tr * 4 + i) * IN_FEAT + k];
                acc[i][0] += xv * wv.x;
                acc[i][1] += xv * wv.y;
                acc[i][2] += xv * wv.z;
                acc[i][3] += xv * wv.w;
            }
        }
        #pragma unroll
        for (int i = 0; i < 4; ++i) {
            const int row = row0 + tr * 4 + i;
            const float dn = rsqrtf(deg[row] + 1.0f);
            ushort4 v;
            v.x = f2bf(acc[i][0] * dn); v.y = f2bf(acc[i][1] * dn);
            v.z = f2bf(acc[i][2] * dn); v.w = f2bf(acc[i][3] * dn);
            *(ushort4*)&hb2[(size_t)row * HIDDEN + tc * 4] = v;
        }
    }
}

// ---------------- W23 = W2 @ W3 ; c0 = b2.W3 + b3 ----------------
__global__ __launch_bounds__(256) void k_w23(const float* __restrict__ W2,
                                             const float* __restrict__ W3,
                                             const float* __restrict__ b2,
                                             const float* __restrict__ b3,
                                             float* __restrict__ W23,
                                             float* __restrict__ c0) {
    const int wid  = blockIdx.x * 4 + (threadIdx.x >> 6);
    const int lane = threadIdx.x & 63;
    if (wid < FDIM) {
        float acc = 0.f;
        #pragma unroll
        for (int c = lane; c < HC2; c += 64) acc += W2[wid * HC2 + c] * W3[c];
        #pragma unroll
        for (int off = 32; off; off >>= 1) acc += __shfl_down(acc, off);
        if (lane == 0) W23[wid] = acc;
    } else if (wid == FDIM) {
        float acc = 0.f;
        #pragma unroll
        for (int c = lane; c < HC2; c += 64) acc += b2[c] * W3[c];
        #pragma unroll
        for (int off = 32; off; off >>= 1) acc += __shfl_down(acc, off);
        if (lane == 0) c0[0] = acc + b3[0];
    }
}

// ---------------- out[g] = c0 ----------------
__global__ __launch_bounds__(256) void k_initout(const float* __restrict__ c0,
                                                 float* __restrict__ out) {
    int g = blockIdx.x * 256 + threadIdx.x;
    if (g < NUM_GRAPHS) out[g] = c0[0];
}

// quarter-wave quad step: group's record -> 8B row slice per lane, 4 FMAs
__device__ __forceinline__ void quad(const uint2 r,
                                     const unsigned short* __restrict__ hb2,
                                     int fq, float4& acc) {
    const unsigned row = r.x & 0x1FFFF;
    const float w = __uint_as_float(r.y);
    const ushort4 hv = *(const ushort4*)(hb2 + (size_t)row * HIDDEN + fq * 4);
    acc.x += w * bf2f(hv.x); acc.y += w * bf2f(hv.y);
    acc.z += w * bf2f(hv.z); acc.w += w * bf2f(hv.w);
}

// per-node epilogue: cross-group reduce, self-loop, relu+b1, dot W23, out atomic
__device__ __forceinline__ void epi(float4 acc, int n, int fq, int lane,
                                    const float* __restrict__ deg,
                                    const unsigned short* __restrict__ hb2,
                                    float4 b1q, const float* __restrict__ W23,
                                    float* __restrict__ out) {
    acc.x += __shfl_xor(acc.x, 16); acc.y += __shfl_xor(acc.y, 16);
    acc.z += __shfl_xor(acc.z, 16); acc.w += __shfl_xor(acc.w, 16);
    acc.x += __shfl_xor(acc.x, 32); acc.y += __shfl_xor(acc.y, 32);
    acc.z += __shfl_xor(acc.z, 32); acc.w += __shfl_xor(acc.w, 32);
    const float dn = rsqrtf(deg[n] + 1.0f);
    const ushort4 hs = *(const ushort4*)(hb2 + (size_t)n * HIDDEN + fq * 4);
    float4 v;
    v.x = fmaxf((acc.x + bf2f(hs.x)) * dn + b1q.x, 0.f);
    v.y = fmaxf((acc.y + bf2f(hs.y)) * dn + b1q.y, 0.f);
    v.z = fmaxf((acc.z + bf2f(hs.z)) * dn + b1q.z, 0.f);
    v.w = fmaxf((acc.w + bf2f(hs.w)) * dn + b1q.w, 0.f);
    const int g = n / NPG, r = n - g * NPG;
    const float4 wv = *(const float4*)(W23 + r * HIDDEN + fq * 4);
    float p = v.x * wv.x + v.y * wv.y + v.z * wv.z + v.w * wv.w;
    p += __shfl_xor(p, 1); p += __shfl_xor(p, 2);
    p += __shfl_xor(p, 4); p += __shfl_xor(p, 8);
    if (lane == 0) atomicAdd(&out[g], p);
}

// ---- pass 3: gather, 2 nodes/wave, quarter-wave rows (4 edges / VMEM) ----
__global__ __launch_bounds__(256) void k_gather(const uint2* __restrict__ adj2,
                                                const unsigned* __restrict__ base2,
                                                const unsigned* __restrict__ ends,
                                                const float* __restrict__ deg,
                                                const unsigned short* __restrict__ hb2,
                                                const float* __restrict__ b1,
                                                const float* __restrict__ W23,
                                                float* __restrict__ out) {
    const int wave = threadIdx.x >> 6, lane = threadIdx.x & 63;
    const int grp = lane >> 4, fq = lane & 15;
    const float4 b1q = *(const float4*)(b1 + fq * 4);
    const int n0 = blockIdx.x * 8 + wave * 2;        // grid = N_NODES/8
    unsigned ka = __builtin_amdgcn_readfirstlane(base2[n0]);
    const unsigned ea = __builtin_amdgcn_readfirstlane(ends[n0]);
    unsigned kb = __builtin_amdgcn_readfirstlane(base2[n0 + 1]);
    const unsigned eb = __builtin_amdgcn_readfirstlane(ends[n0 + 1]);
    float4 accA = {0.f, 0.f, 0.f, 0.f}, accB = {0.f, 0.f, 0.f, 0.f};
    while (ka + 8 <= ea && kb + 8 <= eb) {           // 4 x 512B gathers in flight
        uint2 rA0 = adj2[ka + grp], rA1 = adj2[ka + 4 + grp];
        uint2 rB0 = adj2[kb + grp], rB1 = adj2[kb + 4 + grp];
        quad(rA0, hb2, fq, accA); quad(rB0, hb2, fq, accB);
        quad(rA1, hb2, fq, accA); quad(rB1, hb2, fq, accB);
        ka += 8; kb += 8;
    }
    while (ka + 4 <= ea && kb + 4 <= eb) {
        uint2 rA = adj2[ka + grp], rB = adj2[kb + grp];
        quad(rA, hb2, fq, accA); quad(rB, hb2, fq, accB);
        ka += 4; kb += 4;
    }
    for (; ka + 4 <= ea; ka += 4) { uint2 r = adj2[ka + grp]; quad(r, hb2, fq, accA); }
    for (; kb + 4 <= eb; kb += 4) { uint2 r = adj2[kb + grp]; quad(r, hb2, fq, accB); }
    const int remA = (int)(ea - ka);
    if (remA) {
        uint2 r = adj2[ka + grp];
        if (grp >= remA) { r.x = 0u; r.y = 0u; }
        quad(r, hb2, fq, accA);
    }
    const int remB = (int)(eb - kb);
    if (remB) {
        uint2 r = adj2[kb + grp];
        if (grp >= remB) { r.x = 0u; r.y = 0u; }
        quad(r, hb2, fq, accB);
    }
    epi(accA, n0,     fq, lane, deg, hb2, b1q, W23, out);
    epi(accB, n0 + 1, fq, lane, deg, hb2, b1q, W23, out);
}

extern "C" void kernel_launch(void* const* d_in, const int* in_sizes, int n_in,
                              void* d_out, int out_size, void* d_ws, size_t ws_size,
                              hipStream_t stream) {
    const float* x  = (const float*)d_in[0];
    const int*   ei = (const int*)  d_in[1];
    const float* ew = (const float*)d_in[2];
    const float* W1 = (const float*)d_in[4];
    const float* b1 = (const float*)d_in[5];
    const float* W2 = (const float*)d_in[6];
    const float* b2 = (const float*)d_in[7];
    const float* W3 = (const float*)d_in[8];
    const float* b3 = (const float*)d_in[9];
    float* out = (float*)d_out;

    char* ws = (char*)d_ws;
    unsigned short* hb2  = (unsigned short*)(ws);              // 15,073,280
    uint2*          adj  = (uint2*)   (ws + 15073280);         // 33,914,880 (+pad)
    uint2*          adj2 = (uint2*)   (ws + 48988224);         // 33,914,880 (+pad)
    float*          deg  = (float*)   (ws + 82903168);         // 471,040
    unsigned*       base2= (unsigned*)(ws + 83374208);         // 471,040
    unsigned*       ends = (unsigned*)(ws + 83845248);         // 471,040
    unsigned*       cur  = (unsigned*)(ws + 84316288);         // 1,840
    float*          W23  = (float*)   (ws + 84318128);         // 29,440
    float*          c0   = (float*)   (ws + 84347568);         // 4

    k_initcur<<<2, 256, 0, stream>>>(cur);
    k_part <<<N_EDGES / RPB, 512, 0, stream>>>(ei, ew, cur, adj);
    k_sort2<<<NB, 512, 0, stream>>>(adj, cur, adj2, base2, ends, deg);
    k_h    <<<512, 256, 0, stream>>>(x, W1, deg, hb2);
    k_w23  <<<(FDIM / 4) + 1, 256, 0, stream>>>(W2, W3, b2, b3, W23, c0);
    k_initout<<<4, 256, 0, stream>>>(c0, out);
    k_gather<<<N_NODES / 8, 256, 0, stream>>>(adj2, base2, ends, deg, hb2, b1, W23, out);
}